// Round 6
// baseline (1108.865 us; speedup 1.0000x reference)
//
#include <hip/hip_runtime.h>

// S4 model (B=8, L=4096, H=512, N=16, 4 layers), fully fused pipeline.
// Round 6: force VOP3P packed fp32 (v_pk_fma_f32 / v_pk_mul_f32) via inline asm
// in phase1/phase3 inner loops — round-5 evidence says the compiler scalarized
// the float2 elementwise-fma (VALU busy 66us vs ~30us packed floor).

typedef __attribute__((ext_vector_type(8))) short s16x8;
typedef __attribute__((ext_vector_type(4))) float f32x4;
typedef __attribute__((ext_vector_type(2))) float f32x2;
typedef unsigned short u16;
typedef unsigned int u32;

#define LSEQ 4096
#define HD   512
#define NST  16
#define NP   8     // NST/2 packed pairs
#define NLAYER 4
#define BS   8
#define LC   64
#define NCH  64   // LSEQ / LC

static __device__ __forceinline__ u16 f2bf(float f){
  u32 u = __builtin_bit_cast(u32, f);
  u += 0x7FFFu + ((u >> 16) & 1u);     // round-to-nearest-even
  return (u16)(u >> 16);
}
static __device__ __forceinline__ float bf2f(u16 v){
  u32 u = ((u32)v) << 16;
  return __builtin_bit_cast(float, u);
}
// VOP3P packed fp32 — guaranteed encoding (compiler scalarizes the generic form)
static __device__ __forceinline__ f32x2 pk_fma(f32x2 a, f32x2 b, f32x2 c){
  f32x2 d;
  asm("v_pk_fma_f32 %0, %1, %2, %3" : "=v"(d) : "v"(a), "v"(b), "v"(c));
  return d;
}
static __device__ __forceinline__ f32x2 pk_mul(f32x2 a, f32x2 b){
  f32x2 d;
  asm("v_pk_mul_f32 %0, %1, %2" : "=v"(d) : "v"(a), "v"(b));
  return d;
}

static __device__ __forceinline__ void async16(const void* g, void* l){
  __builtin_amdgcn_global_load_lds((const __attribute__((address_space(1))) unsigned*)g,
                                   (__attribute__((address_space(3))) unsigned*)l,
                                   16, 0, 0);
}

// ---------------- per-layer SSM params: w=exp(dt*A), w^LC, Ct=2*C*(w-1)/A ----------
// params layout per layer (65536 floats):
//   [0)      w  : n*1024 + {0,512} + h
//   [16384)  wLc: n*1024 + {0,512} + h
//   [32768)  Ct : (d*16+n)*1024 + {0,512} + h      (includes the factor 2)
__global__ __launch_bounds__(256) void param_kernel(
    const float* __restrict__ log_dt, const float* __restrict__ A_re,
    const float* __restrict__ A_im, const float* __restrict__ C_re,
    const float* __restrict__ C_im, float* __restrict__ params)
{
  int idx = blockIdx.x*256 + threadIdx.x;        // NLAYER*NST*HD = 32768
  int h = idx & (HD-1);
  int n = (idx >> 9) & (NST-1);
  int layer = idx >> 13;
  float dt  = expf(log_dt[layer*HD + h]);
  float Are = A_re[((layer<<9)+h)*NST + n];
  float Aim = A_im[((layer<<9)+h)*NST + n];
  float ar = Are*dt, ai = Aim*dt;
  float er = expf(ar), sn, cs;
  sincosf(ai, &sn, &cs);
  float wr = er*cs, wi = er*sn;
  float eL = expf((float)LC*ar), snL, csL;
  sincosf((float)LC*ai, &snL, &csL);
  float* P = params + layer*65536;
  P[n*1024 + h]        = wr;
  P[n*1024 + 512 + h]  = wi;
  P[16384 + n*1024 + h]       = eL*csL;
  P[16384 + n*1024 + 512 + h] = eL*snL;
  float den = Are*Are + Aim*Aim;
  float qr = ((wr-1.f)*Are + wi*Aim) / den;      // (w-1)/A = (w-1)*conj(A)/|A|^2
  float qi = (wi*Are - (wr-1.f)*Aim) / den;
  #pragma unroll
  for (int d=0; d<2; d++){
    float Cre = C_re[(((layer*2+d)<<9)+h)*NST + n];
    float Cim = C_im[(((layer*2+d)<<9)+h)*NST + n];
    P[32768 + (d*NST+n)*1024 + h]       = 2.f*(Cre*qr - Cim*qi);
    P[32768 + (d*NST+n)*1024 + 512 + h] = 2.f*(Cre*qi + Cim*qr);
  }
}

__global__ __launch_bounds__(256) void owconv_kernel(const float* __restrict__ ow,
                                                     u16* __restrict__ owbf)
{
  size_t idx = (size_t)blockIdx.x*256 + threadIdx.x;   // 4*1024*512 = 2,097,152
  owbf[idx] = f2bf(ow[idx]);
}

// ---------------- encoder ----------------------------------------------------------
__global__ __launch_bounds__(256) void encoder_kernel(
    const float* __restrict__ x, const float* __restrict__ ew,
    const float* __restrict__ eb, float* __restrict__ hbuf)
{
  size_t idx = (size_t)blockIdx.x*256 + threadIdx.x;   // B*L*H = 16,777,216
  int h = (int)(idx & (HD-1));
  int t = (int)((idx >> 9) & (LSEQ-1));
  int b = (int)(idx >> 21);
  float g = (float)t * (1.0f/4095.0f);
  hbuf[idx] = x[(b<<12) + t]*ew[2*h] + g*ew[2*h+1] + eb[h];
}

// ---------------- ustat: LN stats + write normalized u as bf16 ----------------------
__global__ __launch_bounds__(256) void ustat_kernel(
    const float* __restrict__ hbuf, const float* __restrict__ lnw,
    const float* __restrict__ lnb, u16* __restrict__ ubf)
{
  int row  = (int)((blockIdx.x*256 + threadIdx.x) >> 6);  // 32768 rows
  int lane = threadIdx.x & 63;
  const float* p = hbuf + ((size_t)row << 9) + lane*8;
  float4 a = *(const float4*)p;
  float4 b = *(const float4*)(p+4);
  float s  = a.x+a.y+a.z+a.w + b.x+b.y+b.z+b.w;
  float sq = a.x*a.x+a.y*a.y+a.z*a.z+a.w*a.w + b.x*b.x+b.y*b.y+b.z*b.z+b.w*b.w;
  #pragma unroll
  for (int off=32; off; off>>=1){ s += __shfl_xor(s, off, 64); sq += __shfl_xor(sq, off, 64); }
  float mu = s*(1.f/512.f);
  float var = sq*(1.f/512.f) - mu*mu;
  float rstd = rsqrtf(var + 1e-5f);
  const float* wp = lnw + lane*8;
  const float* bp = lnb + lane*8;
  float4 w0 = *(const float4*)wp, w1 = *(const float4*)(wp+4);
  float4 b0 = *(const float4*)bp, b1 = *(const float4*)(bp+4);
  float u0 = (a.x-mu)*rstd*w0.x + b0.x;
  float u1 = (a.y-mu)*rstd*w0.y + b0.y;
  float u2 = (a.z-mu)*rstd*w0.z + b0.z;
  float u3 = (a.w-mu)*rstd*w0.w + b0.w;
  float u4 = (b.x-mu)*rstd*w1.x + b1.x;
  float u5 = (b.y-mu)*rstd*w1.y + b1.y;
  float u6 = (b.z-mu)*rstd*w1.z + b1.z;
  float u7 = (b.w-mu)*rstd*w1.w + b1.w;
  u32 o0 = (u32)f2bf(u0) | ((u32)f2bf(u1)<<16);
  u32 o1 = (u32)f2bf(u2) | ((u32)f2bf(u3)<<16);
  u32 o2 = (u32)f2bf(u4) | ((u32)f2bf(u5)<<16);
  u32 o3 = (u32)f2bf(u6) | ((u32)f2bf(u7)<<16);
  uint4 pk = make_uint4(o0,o1,o2,o3);
  *(uint4*)(ubf + ((size_t)row << 9) + lane*8) = pk;
}

// ---------------- phase 1: chunk summaries (both dirs), packed fp32 -----------------
// S layout: (((b*2+dir)*NCH + c)*NST + n)*1024 + {0,512} + h
__global__ __launch_bounds__(64) void phase1_kernel(
    const u16* __restrict__ ubf, const float* __restrict__ P, float* __restrict__ S)
{
  int bx = blockIdx.x;                  // ((b*2+dir)*NCH + c)*8 + hg ; 8192 blocks
  int hg  = bx & 7;
  int c   = (bx >> 3) & (NCH-1);
  int dir = (bx >> 9) & 1;
  int b   = bx >> 10;
  int lane = threadIdx.x;
  int hcol = (hg << 6) + lane;
  f32x2 wr2[NP], wn2[NP], wi2[NP];
  #pragma unroll
  for (int j=0;j<NP;j++){
    float wra = P[(2*j)*1024 + hcol],   wrb = P[(2*j+1)*1024 + hcol];
    float wia = P[(2*j)*1024 + 512 + hcol], wib = P[(2*j+1)*1024 + 512 + hcol];
    wr2[j] = (f32x2){wra, wrb};
    wi2[j] = (f32x2){wia, wib};
    wn2[j] = (f32x2){-wia, -wib};
  }
  f32x2 sr2[NP], si2[NP];
  #pragma unroll
  for (int j=0;j<NP;j++){ sr2[j]=(f32x2){0.f,0.f}; si2[j]=(f32x2){0.f,0.f}; }
  int t0 = c * LC;
  const u16* up = ubf + ((size_t)b << 21) + hcol;
  for (int j8=0; j8<LC; j8+=8){
    float uv[8];
    #pragma unroll
    for (int q=0;q<8;q++){
      int jj = j8 + q;
      int t = dir ? (t0 + (LC-1) - jj) : (t0 + jj);
      uv[q] = bf2f(up[(size_t)t << 9]);
    }
    #pragma unroll
    for (int q=0;q<8;q++){
      f32x2 u2 = (f32x2){uv[q], uv[q]};
      #pragma unroll
      for (int j=0;j<NP;j++){
        f32x2 s0 = sr2[j];
        sr2[j] = pk_fma(wr2[j], s0, pk_fma(wn2[j], si2[j], u2));
        si2[j] = pk_fma(wr2[j], si2[j], pk_mul(wi2[j], s0));
      }
    }
  }
  size_t sbase = (((size_t)(b*2+dir)*NCH + c)*NST)*1024 + hcol;
  #pragma unroll
  for (int j=0;j<NP;j++){
    S[sbase + (size_t)(2*j)*1024]         = sr2[j].x;
    S[sbase + (size_t)(2*j)*1024 + 512]   = si2[j].x;
    S[sbase + (size_t)(2*j+1)*1024]       = sr2[j].y;
    S[sbase + (size_t)(2*j+1)*1024 + 512] = si2[j].y;
  }
}

// ---------------- phase 2: inter-chunk scan (in place on S) -------------------------
__global__ __launch_bounds__(256) void phase2_kernel(const float* __restrict__ P,
                                                     float* __restrict__ S)
{
  int f = blockIdx.x*256 + threadIdx.x;     // B*2*NST*HD = 131072
  int h   = f & (HD-1);
  int n   = (f >> 9) & (NST-1);
  int dir = (f >> 13) & 1;
  int b   = f >> 14;
  float wLr = P[16384 + n*1024 + h];
  float wLi = P[16384 + n*1024 + 512 + h];
  size_t base = (((size_t)(b*2+dir)*NCH)*NST + n)*1024 + h;
  const size_t cs = (size_t)NST*1024;       // floats per chunk
  float Xr = 0.f, Xi = 0.f;
  if (dir == 0){
    for (int c=0;c<NCH;c++){
      float Sr = S[base + c*cs], Si = S[base + c*cs + 512];
      float nr = fmaf(wLr, Xr, fmaf(-wLi, Xi, Sr));
      float ni = fmaf(wLr, Xi, fmaf( wLi, Xr, Si));
      Xr = nr; Xi = ni;
      S[base + c*cs] = Xr; S[base + c*cs + 512] = Xi;
    }
  } else {
    for (int cc=0;cc<NCH;cc++){
      int c = NCH-1-cc;
      float Sr = S[base + c*cs], Si = S[base + c*cs + 512];
      S[base + c*cs] = Xr; S[base + c*cs + 512] = Xi;   // boundary BEFORE update
      float nr = fmaf(wLr, Xr, fmaf(-wLi, Xi, Sr));
      float ni = fmaf(wLr, Xi, fmaf( wLi, Xr, Si));
      Xr = nr; Xi = ni;
    }
  }
}

// ---------------- phase 3: packed fp32; fwd->y32; bwd reads, GELU, bf16 into uy -----
// uy is BOTH the bf16 u input and the bf16 y output (read-before-write per slot).
__global__ __launch_bounds__(64) void phase3_kernel(
    u16* __restrict__ uy, const float* __restrict__ Dvec, const float* __restrict__ P,
    const float* __restrict__ S, float* __restrict__ y32)
{
  int bx = blockIdx.x;                 // (b*NCH + c)*8 + hg ; 4096 blocks
  int hg = bx & 7;
  int c  = (bx >> 3) & (NCH-1);
  int b  = bx >> 9;
  int lane = threadIdx.x;
  int hcol = (hg << 6) + lane;
  f32x2 wr2[NP], wn2[NP], wi2[NP];
  #pragma unroll
  for (int j=0;j<NP;j++){
    float wra = P[(2*j)*1024 + hcol],   wrb = P[(2*j+1)*1024 + hcol];
    float wia = P[(2*j)*1024 + 512 + hcol], wib = P[(2*j+1)*1024 + 512 + hcol];
    wr2[j] = (f32x2){wra, wrb};
    wi2[j] = (f32x2){wia, wib};
    wn2[j] = (f32x2){-wia, -wib};
  }
  float Dh = Dvec[hcol];
  int t0 = c * LC;
  u16* up = uy + ((size_t)b << 21) + hcol;
  float* yp = y32 + ((size_t)b << 21) + hcol;

  // ---- forward: y32[t] = u*D + 2Re(Ct0 . x[t]) ----
  {
    f32x2 cr2[NP], cn2[NP], xr2[NP], xi2[NP];
    #pragma unroll
    for (int j=0;j<NP;j++){
      cr2[j] = (f32x2){P[32768 + (2*j)*1024 + hcol],       P[32768 + (2*j+1)*1024 + hcol]};
      cn2[j] = (f32x2){-P[32768 + (2*j)*1024 + 512 + hcol], -P[32768 + (2*j+1)*1024 + 512 + hcol]};
    }
    if (c > 0){
      size_t sb = (((size_t)(b*2+0)*NCH + (c-1))*NST)*1024 + hcol;
      #pragma unroll
      for (int j=0;j<NP;j++){
        xr2[j] = (f32x2){S[sb + (size_t)(2*j)*1024],       S[sb + (size_t)(2*j+1)*1024]};
        xi2[j] = (f32x2){S[sb + (size_t)(2*j)*1024 + 512], S[sb + (size_t)(2*j+1)*1024 + 512]};
      }
    } else {
      #pragma unroll
      for (int j=0;j<NP;j++){ xr2[j]=(f32x2){0.f,0.f}; xi2[j]=(f32x2){0.f,0.f}; }
    }
    for (int j8=0;j8<LC;j8+=8){
      float uv[8];
      #pragma unroll
      for (int q=0;q<8;q++){
        int t = t0 + j8 + q;
        uv[q] = bf2f(up[(size_t)t << 9]);
      }
      #pragma unroll
      for (int q=0;q<8;q++){
        float u = uv[q];
        f32x2 u2 = (f32x2){u, u};
        f32x2 acc2 = (f32x2){u*Dh, 0.f};
        #pragma unroll
        for (int j=0;j<NP;j++){
          f32x2 s0 = xr2[j];
          xr2[j] = pk_fma(wr2[j], s0, pk_fma(wn2[j], xi2[j], u2));
          xi2[j] = pk_fma(wr2[j], xi2[j], pk_mul(wi2[j], s0));
          acc2 = pk_fma(cr2[j], xr2[j], acc2);
          acc2 = pk_fma(cn2[j], xi2[j], acc2);
        }
        yp[(size_t)(t0 + j8 + q) << 9] = acc2.x + acc2.y;
      }
    }
  }
  // ---- backward: y = y32[t] + 2Re(Ct1 . xb[t]); GELU; bf16 store into uy ----
  {
    f32x2 cr2[NP], cn2[NP], xr2[NP], xi2[NP];
    #pragma unroll
    for (int j=0;j<NP;j++){
      cr2[j] = (f32x2){P[32768 + (NST+2*j)*1024 + hcol],        P[32768 + (NST+2*j+1)*1024 + hcol]};
      cn2[j] = (f32x2){-P[32768 + (NST+2*j)*1024 + 512 + hcol], -P[32768 + (NST+2*j+1)*1024 + 512 + hcol]};
    }
    size_t sb = (((size_t)(b*2+1)*NCH + c)*NST)*1024 + hcol;
    #pragma unroll
    for (int j=0;j<NP;j++){
      xr2[j] = (f32x2){S[sb + (size_t)(2*j)*1024],       S[sb + (size_t)(2*j+1)*1024]};
      xi2[j] = (f32x2){S[sb + (size_t)(2*j)*1024 + 512], S[sb + (size_t)(2*j+1)*1024 + 512]};
    }
    for (int j8=0;j8<LC;j8+=8){
      float uv[8], yf[8];
      #pragma unroll
      for (int q=0;q<8;q++){
        int t = t0 + (LC-1) - (j8+q);
        uv[q] = bf2f(up[(size_t)t << 9]);   // read u BEFORE y overwrite below
        yf[q] = yp[(size_t)t << 9];
      }
      #pragma unroll
      for (int q=0;q<8;q++){
        int t = t0 + (LC-1) - (j8+q);
        f32x2 acc2 = (f32x2){yf[q], 0.f};
        #pragma unroll
        for (int j=0;j<NP;j++){
          acc2 = pk_fma(cr2[j], xr2[j], acc2);
          acc2 = pk_fma(cn2[j], xi2[j], acc2);
        }
        float acc = acc2.x + acc2.y;
        float g = 0.5f*acc*(1.f + erff(acc*0.70710678118654752f));
        up[(size_t)t << 9] = f2bf(g);
        float u = uv[q];
        f32x2 u2 = (f32x2){u, u};
        #pragma unroll
        for (int j=0;j<NP;j++){
          f32x2 s0 = xr2[j];
          xr2[j] = pk_fma(wr2[j], s0, pk_fma(wn2[j], xi2[j], u2));
          xi2[j] = pk_fma(wr2[j], xi2[j], pk_mul(wi2[j], s0));
        }
      }
    }
  }
}

// ---------------- GEMM (bf16 MFMA, swizzled global_load_lds staging) + GLU ----------
// LDS slot (r, c) holds global 16B-chunk (c ^ (r&7)) of row r -> conflict-free
// b128 reads (8 lanes per 16B column) while keeping lane-linear DMA dests.
__global__ __launch_bounds__(256) void gemm_glu_kernel(
    const u16* __restrict__ ybf, const u16* __restrict__ owbf,
    const float* __restrict__ ob, float* __restrict__ hbuf)
{
  __shared__ u16 As[128*64];
  __shared__ u16 Bsh[128*64];
  const int tid = threadIdx.x;
  const int wave = tid >> 6, lane = tid & 63;
  const int mt = blockIdx.x >> 3, nt = blockIdx.x & 7;
  const int m0 = mt*128, n0 = nt*64;
  const int row = tid >> 3;           // 0..31
  const int ch  = tid & 7;            // 16B chunk slot 0..7
  f32x4 acc[2][8];
  #pragma unroll
  for (int i=0;i<2;i++)
    #pragma unroll
    for (int j=0;j<8;j++)
      #pragma unroll
      for (int k=0;k<4;k++) acc[i][j][k] = 0.f;

  const int ro = lane & 15, qq = lane >> 4;
  const int sx = ro & 7;              // read-side swizzle key
  for (int k0=0;k0<512;k0+=64){
    __syncthreads();
    #pragma unroll
    for (int p=0;p<4;p++){
      int r = p*32 + row;
      int cs = (ch ^ (r & 7)) << 3;   // swizzled source chunk (u16 units)
      async16(ybf + ((size_t)(m0+r) << 9) + k0 + cs, &As[(r<<6) + (ch<<3)]);
      int br = n0 + (r & 63) + ((r >> 6) << 9);
      async16(owbf + ((size_t)br << 9) + k0 + cs, &Bsh[(r<<6) + (ch<<3)]);
    }
    __syncthreads();
    #pragma unroll
    for (int ks=0;ks<2;ks++){
      s16x8 a[2], bf[8];
      #pragma unroll
      for (int mi=0;mi<2;mi++){
        int g = ks*4 + qq;            // wanted global chunk
        uint4 t = *(const uint4*)(&As[((wave*32 + mi*16 + ro)<<6) + ((g ^ sx)<<3)]);
        a[mi] = __builtin_bit_cast(s16x8, t);
      }
      #pragma unroll
      for (int ni=0;ni<8;ni++){
        int g = ks*4 + qq;
        uint4 t = *(const uint4*)(&Bsh[((ni*16 + ro)<<6) + ((g ^ sx)<<3)]);
        bf[ni] = __builtin_bit_cast(s16x8, t);
      }
      #pragma unroll
      for (int mi=0;mi<2;mi++)
        #pragma unroll
        for (int ni=0;ni<8;ni++)
          acc[mi][ni] = __builtin_amdgcn_mfma_f32_16x16x32_bf16(a[mi], bf[ni], acc[mi][ni], 0, 0, 0);
    }
  }
  // epilogue: z1*sigmoid(z2) + residual
  #pragma unroll
  for (int ni=0;ni<4;ni++){
    int col = n0 + ni*16 + ro;
    float b1 = ob[col], b2 = ob[col + 512];
    #pragma unroll
    for (int mi=0;mi<2;mi++){
      f32x4 z1 = acc[mi][ni], z2 = acc[mi][ni+4];
      #pragma unroll
      for (int rg=0;rg<4;rg++){
        int rowi = m0 + wave*32 + mi*16 + qq*4 + rg;
        float zz1 = z1[rg] + b1;
        float zz2 = z2[rg] + b2;
        float g = zz1 / (1.f + expf(-zz2));
        size_t idx = ((size_t)rowi << 9) + col;
        hbuf[idx] += g;
      }
    }
  }
}

// ---------------- decoder ----------------------------------------------------------
__global__ __launch_bounds__(256) void decoder_kernel(
    const float* __restrict__ hbuf, const float* __restrict__ dec_w,
    const float* __restrict__ dec_b, float* __restrict__ out)
{
  int wid  = (int)((blockIdx.x*256 + threadIdx.x) >> 6);  // row id, 32768 total
  int lane = threadIdx.x & 63;
  const float* p = hbuf + ((size_t)wid << 9) + lane*8;
  float4 a = *(const float4*)p;
  float4 b = *(const float4*)(p+4);
  const float* dw = dec_w + lane*8;
  float4 w0 = *(const float4*)dw;
  float4 w1 = *(const float4*)(dw+4);
  float s = a.x*w0.x + a.y*w0.y + a.z*w0.z + a.w*w0.w
          + b.x*w1.x + b.y*w1.y + b.z*w1.z + b.w*w1.w;
  #pragma unroll
  for (int off=32; off; off>>=1) s += __shfl_xor(s, off, 64);
  if (lane == 0) out[wid] = s + dec_b[0];
}

extern "C" void kernel_launch(void* const* d_in, const int* in_sizes, int n_in,
                              void* d_out, int out_size, void* d_ws, size_t ws_size,
                              hipStream_t stream) {
  const float* x     = (const float*)d_in[0];
  const float* encw  = (const float*)d_in[1];
  const float* encb  = (const float*)d_in[2];
  const float* logdt = (const float*)d_in[3];
  const float* A_re  = (const float*)d_in[4];
  const float* A_im  = (const float*)d_in[5];
  const float* C_re  = (const float*)d_in[6];
  const float* C_im  = (const float*)d_in[7];
  const float* Dv    = (const float*)d_in[8];
  const float* out_w = (const float*)d_in[9];
  const float* out_b = (const float*)d_in[10];
  const float* ln_w  = (const float*)d_in[11];
  const float* ln_b  = (const float*)d_in[12];
  const float* dec_w = (const float*)d_in[13];
  const float* dec_b = (const float*)d_in[14];

  char* ws = (char*)d_ws;
  float*  hbuf   = (float*) (ws);                    //  64 MB
  float*  Sbuf   = (float*) (ws + 67108864);         //  64 MB   (end 134,217,728)
  float*  params = (float*) (ws + 134217728);        //   1 MB   (end 135,266,304)
  u16*    owbf   = (u16*)   (ws + 135266304);        //   4 MB   (end 139,460,608)
  u16*    uy     = (u16*)   (ws + 139460608);        //  32 MB   (end 173,015,040)  u AND y (aliased)
  float*  y32    = (float*) (ws + 173015040);        //  64 MB   (end 240,123,904)

  param_kernel<<<128, 256, 0, stream>>>(logdt, A_re, A_im, C_re, C_im, params);
  owconv_kernel<<<8192, 256, 0, stream>>>(out_w, owbf);
  encoder_kernel<<<65536, 256, 0, stream>>>(x, encw, encb, hbuf);
  for (int layer=0; layer<NLAYER; ++layer){
    const float* P = params + layer*65536;
    ustat_kernel<<<8192, 256, 0, stream>>>(hbuf, ln_w + layer*HD, ln_b + layer*HD, uy);
    phase1_kernel<<<8192, 64, 0, stream>>>(uy, P, Sbuf);
    phase2_kernel<<<512, 256, 0, stream>>>(P, Sbuf);
    phase3_kernel<<<4096, 64, 0, stream>>>(uy, Dv + layer*HD, P, Sbuf, y32);
    gemm_glu_kernel<<<2048, 256, 0, stream>>>(uy, owbf + (size_t)layer*524288,
                                              out_b + layer*1024, hbuf);
  }
  decoder_kernel<<<8192, 256, 0, stream>>>(hbuf, dec_w, dec_b, (float*)d_out);
}

// Round 7
// 1010.274 us; speedup vs baseline: 1.0976x; 1.0976x over previous
//
#include <hip/hip_runtime.h>

// S4 model (B=8, L=4096, H=512, N=16, 4 layers).
// Round 7: chunked scan reformulated as per-h MFMA GEMMs (SSD-style).
//   per layer: ustat (LN->u bf16, [b,t,h]) -> T1 transpose -> [h][bc][s]
//     -> build (A_h = [M|E], W_h from SSM params) -> G1 (chunk summaries, MFMA)
//     -> P2 (inter-chunk scan, writes bf16 states V) -> G2 (y = A@[u;V], GELU, MFMA)
//     -> T2 transpose back to [b,t,h] -> gemm_glu (unchanged) -> hbuf residual.
// Eliminates the scalar-VALU scan kernels (phase1/phase3 ~155us/layer).

typedef __attribute__((ext_vector_type(8))) short s16x8;
typedef __attribute__((ext_vector_type(4))) float f32x4;
typedef unsigned short u16;
typedef unsigned int u32;

#define LSEQ 4096
#define HD   512
#define NST  16
#define NLAYER 4
#define BS   8
#define LC   64
#define NCH  64
#define BC   512   // BS*NCH

static __device__ __forceinline__ u16 f2bf(float f){
  u32 u = __builtin_bit_cast(u32, f);
  u += 0x7FFFu + ((u >> 16) & 1u);
  return (u16)(u >> 16);
}
static __device__ __forceinline__ float bf2f(u16 v){
  u32 u = ((u32)v) << 16;
  return __builtin_bit_cast(float, u);
}
static __device__ __forceinline__ u32 pack2bf(float a, float b){
  return (u32)f2bf(a) | ((u32)f2bf(b) << 16);
}
static __device__ __forceinline__ float gelu_exact(float x){
  // Abramowitz-Stegun 7.1.26 erf, |err|<1.5e-7
  float z = fabsf(x) * 0.70710678118654752f;
  float t = 1.f / (1.f + 0.3275911f * z);
  float p = t*(0.254829592f + t*(-0.284496736f + t*(1.421413741f +
            t*(-1.453152027f + t*1.061405429f))));
  float er = 1.f - p * expf(-z*z);
  er = (x < 0.f) ? -er : er;
  return 0.5f * x * (1.f + er);
}

// ---------------- params: w=exp(dt*A), w^LC, Ct=2*C*(w-1)/A (per layer, 65536 f) ----
__global__ __launch_bounds__(256) void param_kernel(
    const float* __restrict__ log_dt, const float* __restrict__ A_re,
    const float* __restrict__ A_im, const float* __restrict__ C_re,
    const float* __restrict__ C_im, float* __restrict__ params)
{
  int idx = blockIdx.x*256 + threadIdx.x;
  int h = idx & (HD-1);
  int n = (idx >> 9) & (NST-1);
  int layer = idx >> 13;
  float dt  = expf(log_dt[layer*HD + h]);
  float Are = A_re[((layer<<9)+h)*NST + n];
  float Aim = A_im[((layer<<9)+h)*NST + n];
  float ar = Are*dt, ai = Aim*dt;
  float er = expf(ar), sn, cs;
  sincosf(ai, &sn, &cs);
  float wr = er*cs, wi = er*sn;
  float eL = expf((float)LC*ar), snL, csL;
  sincosf((float)LC*ai, &snL, &csL);
  float* P = params + layer*65536;
  P[n*1024 + h]        = wr;
  P[n*1024 + 512 + h]  = wi;
  P[16384 + n*1024 + h]       = eL*csL;
  P[16384 + n*1024 + 512 + h] = eL*snL;
  float den = Are*Are + Aim*Aim;
  float qr = ((wr-1.f)*Are + wi*Aim) / den;
  float qi = (wi*Are - (wr-1.f)*Aim) / den;
  #pragma unroll
  for (int d=0; d<2; d++){
    float Cre = C_re[(((layer*2+d)<<9)+h)*NST + n];
    float Cim = C_im[(((layer*2+d)<<9)+h)*NST + n];
    P[32768 + (d*NST+n)*1024 + h]       = 2.f*(Cre*qr - Cim*qi);
    P[32768 + (d*NST+n)*1024 + 512 + h] = 2.f*(Cre*qi + Cim*qr);
  }
}

__global__ __launch_bounds__(256) void owconv_kernel(const float* __restrict__ ow,
                                                     u16* __restrict__ owbf)
{
  size_t idx = (size_t)blockIdx.x*256 + threadIdx.x;
  owbf[idx] = f2bf(ow[idx]);
}

__global__ __launch_bounds__(256) void encoder_kernel(
    const float* __restrict__ x, const float* __restrict__ ew,
    const float* __restrict__ eb, float* __restrict__ hbuf)
{
  size_t idx = (size_t)blockIdx.x*256 + threadIdx.x;
  int h = (int)(idx & (HD-1));
  int t = (int)((idx >> 9) & (LSEQ-1));
  int b = (int)(idx >> 21);
  float g = (float)t * (1.0f/4095.0f);
  hbuf[idx] = x[(b<<12) + t]*ew[2*h] + g*ew[2*h+1] + eb[h];
}

// ---------------- ustat: LN stats + normalized u bf16 into uy[b,t,h] ---------------
__global__ __launch_bounds__(256) void ustat_kernel(
    const float* __restrict__ hbuf, const float* __restrict__ lnw,
    const float* __restrict__ lnb, u16* __restrict__ ubf)
{
  int row  = (int)((blockIdx.x*256 + threadIdx.x) >> 6);
  int lane = threadIdx.x & 63;
  const float* p = hbuf + ((size_t)row << 9) + lane*8;
  float4 a = *(const float4*)p;
  float4 b = *(const float4*)(p+4);
  float s  = a.x+a.y+a.z+a.w + b.x+b.y+b.z+b.w;
  float sq = a.x*a.x+a.y*a.y+a.z*a.z+a.w*a.w + b.x*b.x+b.y*b.y+b.z*b.z+b.w*b.w;
  #pragma unroll
  for (int off=32; off; off>>=1){ s += __shfl_xor(s, off, 64); sq += __shfl_xor(sq, off, 64); }
  float mu = s*(1.f/512.f);
  float var = sq*(1.f/512.f) - mu*mu;
  float rstd = rsqrtf(var + 1e-5f);
  const float* wp = lnw + lane*8;
  const float* bp = lnb + lane*8;
  float4 w0 = *(const float4*)wp, w1 = *(const float4*)(wp+4);
  float4 b0 = *(const float4*)bp, b1 = *(const float4*)(bp+4);
  u32 o0 = pack2bf((a.x-mu)*rstd*w0.x + b0.x, (a.y-mu)*rstd*w0.y + b0.y);
  u32 o1 = pack2bf((a.z-mu)*rstd*w0.z + b0.z, (a.w-mu)*rstd*w0.w + b0.w);
  u32 o2 = pack2bf((b.x-mu)*rstd*w1.x + b1.x, (b.y-mu)*rstd*w1.y + b1.y);
  u32 o3 = pack2bf((b.z-mu)*rstd*w1.z + b1.z, (b.w-mu)*rstd*w1.w + b1.w);
  *(uint4*)(ubf + ((size_t)row << 9) + lane*8) = make_uint4(o0,o1,o2,o3);
}

// ---------------- T1: uy[b,t,h] -> uT[h][bc][t]  (one block per bc) ----------------
__global__ __launch_bounds__(256) void t1_kernel(const u16* __restrict__ uy,
                                                 u16* __restrict__ uT)
{
  __shared__ u32 tile[512*33];   // [h][t-pair], pitch 33 dwords
  int bc = blockIdx.x, tid = threadIdx.x;
  const u16* src = uy + ((size_t)bc << 15);    // rows (bc*64 + t)*512
  #pragma unroll
  for (int it=0; it<8; ++it){
    int ho = (tid & 7) + it*8;                 // h-octet 0..63
    int tp = (tid >> 3) & 31;                  // t-pair 0..31
    const u16* r0 = src + ((size_t)(2*tp) << 9) + ho*8;
    uint4 a = *(const uint4*)r0;               // t even, h = ho*8..+8
    uint4 b = *(const uint4*)(r0 + 512);       // t odd
    u32 ua[4] = {a.x,a.y,a.z,a.w}, ub[4] = {b.x,b.y,b.z,b.w};
    #pragma unroll
    for (int w=0; w<4; ++w){
      u32 lo = (ua[w] & 0xFFFFu) | (ub[w] << 16);          // h = ho*8+2w
      u32 hi = (ua[w] >> 16) | (ub[w] & 0xFFFF0000u);      // h = ho*8+2w+1
      tile[(ho*8 + 2*w    )*33 + tp] = lo;
      tile[(ho*8 + 2*w + 1)*33 + tp] = hi;
    }
  }
  __syncthreads();
  #pragma unroll
  for (int it=0; it<16; ++it){
    int linear = it*256 + tid;
    int h = linear >> 3, sg = linear & 7;
    uint4 v = *(const uint4*)&tile[h*33 + sg*4];
    *(uint4*)(uT + ((size_t)h*BC + bc)*64 + sg*8) = v;
  }
}

// ---------------- build: A_h = [M|E] (64x128) and W_h (64x64), bf16 ----------------
// Abuf[h][t][k] k-pitch 128; Wbuf[h][r][s] s-pitch 64.
__global__ __launch_bounds__(64) void build_kernel(
    const float* __restrict__ logdt, const float* __restrict__ Are_,
    const float* __restrict__ Aim_, const float* __restrict__ P,
    const float* __restrict__ Dv, u16* __restrict__ Abuf, u16* __restrict__ Wbuf)
{
  __shared__ float pr[65][16], pi[65][16], kk0[64], kk1[64];
  int h = blockIdx.x, d = threadIdx.x;       // d = 0..63
  float dt = expf(logdt[h]);
  float k0v = 0.f, k1v = 0.f;
  #pragma unroll
  for (int n=0; n<NST; ++n){
    float ar = Are_[h*NST+n]*dt, ai = Aim_[h*NST+n]*dt;
    float er = expf(ar*(float)d), sn, cs;
    sincosf(ai*(float)d, &sn, &cs);
    float wr = er*cs, wi = er*sn;
    pr[d][n] = wr; pi[d][n] = wi;
    if (d == 63){
      float er2 = expf(ar*64.f), sn2, cs2;
      sincosf(ai*64.f, &sn2, &cs2);
      pr[64][n] = er2*cs2; pi[64][n] = er2*sn2;
    }
    float c0r = P[32768 + n*1024 + h],      c0i = P[32768 + n*1024 + 512 + h];
    float c1r = P[32768 + (16+n)*1024 + h], c1i = P[32768 + (16+n)*1024 + 512 + h];
    k0v += c0r*wr - c0i*wi;
    k1v += c1r*wr - c1i*wi;
  }
  kk0[d] = k0v; kk1[d] = k1v;
  __syncthreads();
  // ---- W row r = d ----
  {
    int r = d;
    u32* wdst = (u32*)(Wbuf + (size_t)h*4096 + r*64);
    int n = r & 15;
    #pragma unroll
    for (int s2=0; s2<32; ++s2){
      float va, vb;
      int s0 = 2*s2, s1 = 2*s2+1;
      if      (r < 16){ va = pr[63-s0][n]; vb = pr[63-s1][n]; }
      else if (r < 32){ va = pi[63-s0][n]; vb = pi[63-s1][n]; }
      else if (r < 48){ va = pr[s0][n];    vb = pr[s1][n]; }
      else            { va = pi[s0][n];    vb = pi[s1][n]; }
      wdst[s2] = pack2bf(va, vb);
    }
  }
  // ---- A row t = d ----
  {
    int t = d;
    float Dh = Dv[h];
    u32* adst = (u32*)(Abuf + (size_t)h*8192 + t*128);
    // M part (k = 0..63)
    #pragma unroll
    for (int j2=0; j2<32; ++j2){
      float va, vb;
      int j0 = 2*j2, j1 = 2*j2+1;
      va = (j0 < t) ? kk0[t-j0] : ((j0 == t) ? (kk0[0] + Dh) : kk1[j0-t-1]);
      vb = (j1 < t) ? kk0[t-j1] : ((j1 == t) ? (kk0[0] + Dh) : kk1[j1-t-1]);
      adst[j2] = pack2bf(va, vb);
    }
    // E part (k = 64..127): [64+n]=Re(Ct0 w^{t+1}), [80+n]=-Im(Ct0 w^{t+1}),
    //                       [96+n]=Re(Ct1 w^{63-t}), [112+n]=-Im(Ct1 w^{63-t})
    float e[64];
    #pragma unroll
    for (int n=0; n<NST; ++n){
      float c0r = P[32768 + n*1024 + h],      c0i = P[32768 + n*1024 + 512 + h];
      float c1r = P[32768 + (16+n)*1024 + h], c1i = P[32768 + (16+n)*1024 + 512 + h];
      float ar = pr[t+1][n], ai = pi[t+1][n];
      float br = pr[63-t][n], bi = pi[63-t][n];
      e[n]      = c0r*ar - c0i*ai;
      e[16+n]   = -(c0r*ai + c0i*ar);
      e[32+n]   = c1r*br - c1i*bi;
      e[48+n]   = -(c1r*bi + c1i*br);
    }
    #pragma unroll
    for (int g=0; g<32; ++g) adst[32+g] = pack2bf(e[2*g], e[2*g+1]);
  }
}

// ---------------- G1: chunk summaries  Sraw[h][bc][r] = W_h @ uT_h (bf16 out) -------
__global__ __launch_bounds__(256) void g1_kernel(
    const u16* __restrict__ Wbuf, const u16* __restrict__ uT, u16* __restrict__ Sraw)
{
  int h = blockIdx.x;
  int tid = threadIdx.x, wave = tid >> 6, lane = tid & 63;
  int ro = lane & 15, qq = lane >> 4;
  const u16* Wh = Wbuf + (size_t)h*4096;
  const u16* Uh = uT + (size_t)h*BC*64;
  f32x4 acc[4][8];
  #pragma unroll
  for (int i=0;i<4;i++)
    #pragma unroll
    for (int j=0;j<8;j++)
      #pragma unroll
      for (int k=0;k<4;k++) acc[i][j][k] = 0.f;
  #pragma unroll
  for (int ks=0; ks<2; ++ks){
    s16x8 a[4], b[8];
    #pragma unroll
    for (int mt=0; mt<4; ++mt){
      uint4 v = *(const uint4*)(Wh + (mt*16 + ro)*64 + ks*32 + qq*8);
      a[mt] = __builtin_bit_cast(s16x8, v);
    }
    #pragma unroll
    for (int nt=0; nt<8; ++nt){
      int bc = wave*128 + nt*16 + ro;
      uint4 v = *(const uint4*)(Uh + (size_t)bc*64 + ks*32 + qq*8);
      b[nt] = __builtin_bit_cast(s16x8, v);
    }
    #pragma unroll
    for (int mt=0; mt<4; ++mt)
      #pragma unroll
      for (int nt=0; nt<8; ++nt)
        acc[mt][nt] = __builtin_amdgcn_mfma_f32_16x16x32_bf16(a[mt], b[nt], acc[mt][nt], 0, 0, 0);
  }
  // store: rows r = mt*16 + qq*4 + rg, col bc; pack 4 bf16 -> 8B
  #pragma unroll
  for (int mt=0; mt<4; ++mt)
    #pragma unroll
    for (int nt=0; nt<8; ++nt){
      int bc = wave*128 + nt*16 + ro;
      int r0 = mt*16 + qq*4;
      u32 lo = pack2bf(acc[mt][nt][0], acc[mt][nt][1]);
      u32 hi = pack2bf(acc[mt][nt][2], acc[mt][nt][3]);
      *(uint2*)(Sraw + ((size_t)h*BC + bc)*64 + r0) = make_uint2(lo, hi);
    }
}

// ---------------- P2: inter-chunk scan -> entry/boundary states V (bf16) ------------
// Sraw rows: [0:16] fwd Re, [16:32] fwd Im, [32:48] bwd Re, [48:64] bwd Im.
// V rows: [0:16]=Xr entry, [16:32]=Xi entry, [32:48]=Br, [48:64]=Bi.
__global__ __launch_bounds__(256) void p2_kernel(
    const float* __restrict__ P, const u16* __restrict__ Sraw, u16* __restrict__ V)
{
  int gid = blockIdx.x*256 + threadIdx.x;    // 512 h x 8 b x 32
  int k = gid & 31;
  int b = (gid >> 5) & 7;
  int h = gid >> 8;
  int dir = k >> 4, n = k & 15;
  float wLr = P[16384 + n*1024 + h];
  float wLi = P[16384 + n*1024 + 512 + h];
  const u16* sp = Sraw + ((size_t)h*BC + b*64)*64;
  u16*       vp = V    + ((size_t)h*BC + b*64)*64;
  float Xr = 0.f, Xi = 0.f;
  if (dir == 0){
    for (int c=0; c<NCH; ++c){
      vp[c*64 + n]      = f2bf(Xr);
      vp[c*64 + 16 + n] = f2bf(Xi);
      float sr = bf2f(sp[c*64 + n]), si = bf2f(sp[c*64 + 16 + n]);
      float nr = fmaf(wLr, Xr, fmaf(-wLi, Xi, sr));
      float ni = fmaf(wLr, Xi, fmaf( wLi, Xr, si));
      Xr = nr; Xi = ni;
    }
  } else {
    for (int cc=0; cc<NCH; ++cc){
      int c = NCH-1-cc;
      vp[c*64 + 32 + n] = f2bf(Xr);
      vp[c*64 + 48 + n] = f2bf(Xi);
      float sr = bf2f(sp[c*64 + 32 + n]), si = bf2f(sp[c*64 + 48 + n]);
      float nr = fmaf(wLr, Xr, fmaf(-wLi, Xi, sr));
      float ni = fmaf(wLr, Xi, fmaf( wLi, Xr, si));
      Xr = nr; Xi = ni;
    }
  }
}

// ---------------- G2: y_T[h][bc][t] = gelu(A_h @ [uT; V]) (bf16) --------------------
__global__ __launch_bounds__(256) void g2_kernel(
    const u16* __restrict__ Abuf, const u16* __restrict__ uT,
    const u16* __restrict__ V, u16* __restrict__ yT)
{
  int h = blockIdx.x;
  int tid = threadIdx.x, wave = tid >> 6, lane = tid & 63;
  int ro = lane & 15, qq = lane >> 4;
  const u16* Ah = Abuf + (size_t)h*8192;
  const u16* Uh = uT + (size_t)h*BC*64;
  const u16* Vh = V  + (size_t)h*BC*64;
  f32x4 acc[4][8];
  #pragma unroll
  for (int i=0;i<4;i++)
    #pragma unroll
    for (int j=0;j<8;j++)
      #pragma unroll
      for (int k=0;k<4;k++) acc[i][j][k] = 0.f;
  #pragma unroll
  for (int ks=0; ks<4; ++ks){
    const u16* Bsrc = (ks < 2) ? Uh : Vh;
    int koff = (ks & 1)*32 + qq*8;
    s16x8 a[4], b[8];
    #pragma unroll
    for (int mt=0; mt<4; ++mt){
      uint4 v = *(const uint4*)(Ah + (mt*16 + ro)*128 + ks*32 + qq*8);
      a[mt] = __builtin_bit_cast(s16x8, v);
    }
    #pragma unroll
    for (int nt=0; nt<8; ++nt){
      int bc = wave*128 + nt*16 + ro;
      uint4 v = *(const uint4*)(Bsrc + (size_t)bc*64 + koff);
      b[nt] = __builtin_bit_cast(s16x8, v);
    }
    #pragma unroll
    for (int mt=0; mt<4; ++mt)
      #pragma unroll
      for (int nt=0; nt<8; ++nt)
        acc[mt][nt] = __builtin_amdgcn_mfma_f32_16x16x32_bf16(a[mt], b[nt], acc[mt][nt], 0, 0, 0);
  }
  #pragma unroll
  for (int mt=0; mt<4; ++mt)
    #pragma unroll
    for (int nt=0; nt<8; ++nt){
      int bc = wave*128 + nt*16 + ro;
      int t0 = mt*16 + qq*4;
      u32 lo = pack2bf(gelu_exact(acc[mt][nt][0]), gelu_exact(acc[mt][nt][1]));
      u32 hi = pack2bf(gelu_exact(acc[mt][nt][2]), gelu_exact(acc[mt][nt][3]));
      *(uint2*)(yT + ((size_t)h*BC + bc)*64 + t0) = make_uint2(lo, hi);
    }
}

// ---------------- T2: yT[h][bc][t] -> uy[b,t,h] (one block per bc) ------------------
__global__ __launch_bounds__(256) void t2_kernel(const u16* __restrict__ yT,
                                                 u16* __restrict__ uy)
{
  __shared__ u32 tile[64*257];   // [t][h-pair], pitch 257 dwords
  int bc = blockIdx.x, tid = threadIdx.x;
  #pragma unroll
  for (int it=0; it<8; ++it){
    int sg = tid & 7;                      // t-octet 0..7
    int hp = it*32 + (tid >> 3);           // h-pair 0..255
    const u16* s0 = yT + ((size_t)(2*hp)*BC + bc)*64 + sg*8;
    uint4 a = *(const uint4*)s0;           // h even, t = sg*8..+8
    uint4 b = *(const uint4*)(s0 + (size_t)BC*64);  // h odd
    u32 ua[4] = {a.x,a.y,a.z,a.w}, ub[4] = {b.x,b.y,b.z,b.w};
    #pragma unroll
    for (int w=0; w<4; ++w){
      u32 lo = (ua[w] & 0xFFFFu) | (ub[w] << 16);
      u32 hi = (ua[w] >> 16) | (ub[w] & 0xFFFF0000u);
      tile[(sg*8 + 2*w    )*257 + hp] = lo;
      tile[(sg*8 + 2*w + 1)*257 + hp] = hi;
    }
  }
  __syncthreads();
  #pragma unroll
  for (int it=0; it<16; ++it){
    int linear = it*256 + tid;
    int t = linear >> 6, sg = linear & 63;
    uint4 v = *(const uint4*)&tile[t*257 + sg*4];
    *(uint4*)(uy + ((size_t)(bc*64 + t) << 9) + sg*8) = v;
  }
}

// ---------------- GEMM (bf16 MFMA, swizzled global_load_lds) + GLU + residual -------
static __device__ __forceinline__ void async16(const void* g, void* l){
  __builtin_amdgcn_global_load_lds((const __attribute__((address_space(1))) unsigned*)g,
                                   (__attribute__((address_space(3))) unsigned*)l,
                                   16, 0, 0);
}
__global__ __launch_bounds__(256) void gemm_glu_kernel(
    const u16* __restrict__ ybf, const u16* __restrict__ owbf,
    const float* __restrict__ ob, float* __restrict__ hbuf)
{
  __shared__ u16 As[128*64];
  __shared__ u16 Bsh[128*64];
  const int tid = threadIdx.x;
  const int wave = tid >> 6, lane = tid & 63;
  const int mt = blockIdx.x >> 3, nt = blockIdx.x & 7;
  const int m0 = mt*128, n0 = nt*64;
  const int row = tid >> 3;
  const int ch  = tid & 7;
  f32x4 acc[2][8];
  #pragma unroll
  for (int i=0;i<2;i++)
    #pragma unroll
    for (int j=0;j<8;j++)
      #pragma unroll
      for (int k=0;k<4;k++) acc[i][j][k] = 0.f;

  const int ro = lane & 15, qq = lane >> 4;
  const int sx = ro & 7;
  for (int k0=0;k0<512;k0+=64){
    __syncthreads();
    #pragma unroll
    for (int p=0;p<4;p++){
      int r = p*32 + row;
      int cs = (ch ^ (r & 7)) << 3;
      async16(ybf + ((size_t)(m0+r) << 9) + k0 + cs, &As[(r<<6) + (ch<<3)]);
      int br = n0 + (r & 63) + ((r >> 6) << 9);
      async16(owbf + ((size_t)br << 9) + k0 + cs, &Bsh[(r<<6) + (ch<<3)]);
    }
    __syncthreads();
    #pragma unroll
    for (int ks=0;ks<2;ks++){
      s16x8 a[2], bf[8];
      #pragma unroll
      for (int mi=0;mi<2;mi++){
        int g = ks*4 + qq;
        uint4 t = *(const uint4*)(&As[((wave*32 + mi*16 + ro)<<6) + ((g ^ sx)<<3)]);
        a[mi] = __builtin_bit_cast(s16x8, t);
      }
      #pragma unroll
      for (int ni=0;ni<8;ni++){
        int g = ks*4 + qq;
        uint4 t = *(const uint4*)(&Bsh[((ni*16 + ro)<<6) + ((g ^ sx)<<3)]);
        bf[ni] = __builtin_bit_cast(s16x8, t);
      }
      #pragma unroll
      for (int mi=0;mi<2;mi++)
        #pragma unroll
        for (int ni=0;ni<8;ni++)
          acc[mi][ni] = __builtin_amdgcn_mfma_f32_16x16x32_bf16(a[mi], bf[ni], acc[mi][ni], 0, 0, 0);
    }
  }
  #pragma unroll
  for (int ni=0;ni<4;ni++){
    int col = n0 + ni*16 + ro;
    float b1 = ob[col], b2 = ob[col + 512];
    #pragma unroll
    for (int mi=0;mi<2;mi++){
      f32x4 z1 = acc[mi][ni], z2 = acc[mi][ni+4];
      #pragma unroll
      for (int rg=0;rg<4;rg++){
        int rowi = m0 + wave*32 + mi*16 + qq*4 + rg;
        float zz1 = z1[rg] + b1;
        float zz2 = z2[rg] + b2;
        float g = zz1 / (1.f + expf(-zz2));
        hbuf[((size_t)rowi << 9) + col] += g;
      }
    }
  }
}

// ---------------- decoder ----------------------------------------------------------
__global__ __launch_bounds__(256) void decoder_kernel(
    const float* __restrict__ hbuf, const float* __restrict__ dec_w,
    const float* __restrict__ dec_b, float* __restrict__ out)
{
  int wid  = (int)((blockIdx.x*256 + threadIdx.x) >> 6);
  int lane = threadIdx.x & 63;
  const float* p = hbuf + ((size_t)wid << 9) + lane*8;
  float4 a = *(const float4*)p;
  float4 b = *(const float4*)(p+4);
  const float* dw = dec_w + lane*8;
  float4 w0 = *(const float4*)dw;
  float4 w1 = *(const float4*)(dw+4);
  float s = a.x*w0.x + a.y*w0.y + a.z*w0.z + a.w*w0.w
          + b.x*w1.x + b.y*w1.y + b.z*w1.z + b.w*w1.w;
  #pragma unroll
  for (int off=32; off; off>>=1) s += __shfl_xor(s, off, 64);
  if (lane == 0) out[wid] = s + dec_b[0];
}

extern "C" void kernel_launch(void* const* d_in, const int* in_sizes, int n_in,
                              void* d_out, int out_size, void* d_ws, size_t ws_size,
                              hipStream_t stream) {
  const float* x     = (const float*)d_in[0];
  const float* encw  = (const float*)d_in[1];
  const float* encb  = (const float*)d_in[2];
  const float* logdt = (const float*)d_in[3];
  const float* A_re  = (const float*)d_in[4];
  const float* A_im  = (const float*)d_in[5];
  const float* C_re  = (const float*)d_in[6];
  const float* C_im  = (const float*)d_in[7];
  const float* Dv    = (const float*)d_in[8];
  const float* out_w = (const float*)d_in[9];
  const float* out_b = (const float*)d_in[10];
  const float* ln_w  = (const float*)d_in[11];
  const float* ln_b  = (const float*)d_in[12];
  const float* dec_w = (const float*)d_in[13];
  const float* dec_b = (const float*)d_in[14];

  char* ws = (char*)d_ws;
  float*  hbuf   = (float*) (ws);                    //  64 MiB
  u16*    uy     = (u16*)   (ws + 67108864);         //  32 MiB
  u16*    uT     = (u16*)   (ws + 100663296);        //  32 MiB
  u16*    Sraw   = (u16*)   (ws + 134217728);        //  32 MiB (later aliased as yT)
  u16*    Vbuf   = (u16*)   (ws + 167772160);        //  32 MiB
  u16*    owbf   = (u16*)   (ws + 201326592);        //   4 MiB
  float*  params = (float*) (ws + 205520896);        //   1 MiB
  u16*    Abuf   = (u16*)   (ws + 206569472);        //   8 MiB
  u16*    Wbuf   = (u16*)   (ws + 214958080);        //   4 MiB (end 219,152,384)
  u16*    yT     = Sraw;                              // alias: Sraw dead after P2

  param_kernel<<<128, 256, 0, stream>>>(logdt, A_re, A_im, C_re, C_im, params);
  owconv_kernel<<<8192, 256, 0, stream>>>(out_w, owbf);
  encoder_kernel<<<65536, 256, 0, stream>>>(x, encw, encb, hbuf);
  for (int layer=0; layer<NLAYER; ++layer){
    const float* P = params + layer*65536;
    ustat_kernel<<<8192, 256, 0, stream>>>(hbuf, ln_w + layer*HD, ln_b + layer*HD, uy);
    t1_kernel<<<512, 256, 0, stream>>>(uy, uT);
    build_kernel<<<512, 64, 0, stream>>>(logdt + layer*HD, A_re + layer*HD*NST,
                                         A_im + layer*HD*NST, P, Dv + layer*HD,
                                         Abuf, Wbuf);
    g1_kernel<<<512, 256, 0, stream>>>(Wbuf, uT, Sraw);
    p2_kernel<<<512, 256, 0, stream>>>(P, Sraw, Vbuf);
    g2_kernel<<<512, 256, 0, stream>>>(Abuf, uT, Vbuf, yT);
    t2_kernel<<<512, 256, 0, stream>>>(yT, uy);
    gemm_glu_kernel<<<2048, 256, 0, stream>>>(uy, owbf + (size_t)layer*524288,
                                              out_b + layer*1024, hbuf);
  }
  decoder_kernel<<<8192, 256, 0, stream>>>(hbuf, dec_w, dec_b, (float*)d_out);
}